// Round 1
// baseline (505.556 us; speedup 1.0000x reference)
//
#include <hip/hip_runtime.h>

#define N_NODES 8192
#define CAP 128    // neighbor capacity; Binomial(8192,1/256): P(deg>128) ~ 0
#define ETILE 16   // nodes per encoder tile
#define DTILE 8    // nodes per decoder tile
constexpr int AST = 132;  // activation LDS row stride (floats), 16B-aligned
constexpr int WST = 129;  // weight LDS row stride (k-major), +1 pad

typedef unsigned u32x4 __attribute__((ext_vector_type(4)));

// ---------------------------------------------------------------------------
// LDS-resident MLP layer for a tile of TILE nodes, 256 threads.
// SCALEMODE: 0 = none, 1 = rowscale[node] (mask).
// ---------------------------------------------------------------------------
template <int TILE, int K, int KSPLIT, int F, bool RELU, bool BIAS, int SCALEMODE>
__device__ __forceinline__ void layer_op(
    const float (*__restrict__ A0)[AST], const float (*__restrict__ A1)[AST],
    float (*__restrict__ Aout)[AST], float (*__restrict__ Wb)[WST],
    const float* __restrict__ W, const float* __restrict__ bias,
    float* __restrict__ gout, const float* __restrict__ rowscale,
    int n0, int t) {
  constexpr int KC = 32;
  constexpr int NCH = K / KC;
  constexpr int ACT = (F * TILE < 256) ? F * TILE : 256;
  constexpr int RS = ACT / F;
  constexpr int RPT = TILE / RS;
  const int c = t % F;
  const int rb = t / F;
  float acc[RPT];
#pragma unroll
  for (int i = 0; i < RPT; ++i) acc[i] = 0.f;

  for (int ch = 0; ch < NCH; ++ch) {
#pragma unroll
    for (int i = 0; i < (F * KC + 255) / 256; ++i) {  // stage W chunk, k-major
      int lin = t + i * 256;
      if ((F * KC) % 256 == 0 || lin < F * KC) {
        int k = lin % KC, f = lin / KC;
        Wb[k][f] = W[(size_t)f * K + ch * KC + k];
      }
    }
    __syncthreads();
    if (t < ACT) {
      const float (*__restrict__ As)[AST] = (ch * KC < KSPLIT) ? A0 : A1;
      const int kb = (ch * KC < KSPLIT) ? ch * KC : ch * KC - KSPLIT;
#pragma unroll
      for (int kg = 0; kg < KC / 4; ++kg) {
        float w0 = Wb[kg * 4 + 0][c];
        float w1v = Wb[kg * 4 + 1][c];
        float w2v = Wb[kg * 4 + 2][c];
        float w3v = Wb[kg * 4 + 3][c];
#pragma unroll
        for (int i = 0; i < RPT; ++i) {
          const float4 a = *(const float4*)&As[rb + i * RS][kb + kg * 4];
          acc[i] = fmaf(a.x, w0, acc[i]);
          acc[i] = fmaf(a.y, w1v, acc[i]);
          acc[i] = fmaf(a.z, w2v, acc[i]);
          acc[i] = fmaf(a.w, w3v, acc[i]);
        }
      }
    }
    __syncthreads();
  }
  if (t < ACT) {
#pragma unroll
    for (int i = 0; i < RPT; ++i) {
      float v = acc[i];
      if (BIAS) v += bias[c];
      if (RELU) v = fmaxf(v, 0.f);
      int node = n0 + rb + i * RS;
      if (SCALEMODE == 1) v *= rowscale[node];
      if (Aout) Aout[rb + i * RS][c] = v;
      if (gout) gout[(size_t)node * F + c] = v;
    }
  }
}

// ---------------------------------------------------------------------------
// Kernel A: fused scan || encode. Blocks with (bid%5)<4 scan adj rows into
// CSR (+dinv); blocks with (bid%5)==4 run the encoder MLP producing h and
// UNSCALED msg = h @ wg.T. Independence: encode no longer reads cnt (the
// dinv_j scaling moved into the gather), so scan/encode can overlap freely.
// Scan chunk order is permuted by (row&3): all co-resident waves previously
// sat in the SAME 8KB window mod the 32KB row stride (channel-phase alias);
// the permutation spreads concurrent traffic over the full 32KB stride.
// ---------------------------------------------------------------------------
__global__ __launch_bounds__(256) void fused_scan_encode_kernel(
    const float* __restrict__ adj, int* __restrict__ cnt,
    float* __restrict__ dinv, int* __restrict__ nbr,
    const float* __restrict__ x,
    const float* __restrict__ w1, const float* __restrict__ b1,
    const float* __restrict__ w2, const float* __restrict__ b2,
    const float* __restrict__ wg,
    float* __restrict__ h_out, float* __restrict__ msg_out) {
  __shared__ float bufA[ETILE][AST];
  __shared__ float bufB[ETILE][AST];
  __shared__ float Wb[32][WST];
  const int t = threadIdx.x;
  const int q = blockIdx.x / 5;
  const int r5 = blockIdx.x % 5;

  if (r5 < 4) {
    // ---- scan path: one row per wave, zero barriers, chunk double-buffer,
    // nontemporal streaming loads, chunk order staggered by row&3.
    const int lane = t & 63;
    const int row = (q * 4 + r5) * 4 + (t >> 6);
    const u32x4* rowp = (const u32x4*)(adj + (size_t)row * N_NODES);
    const int p0 = row & 3;  // stagger phase
    u32x4 v[8], vn[8];
    {
      const u32x4* cp = rowp + p0 * 512;
#pragma unroll
      for (int i = 0; i < 8; ++i) v[i] = __builtin_nontemporal_load(&cp[i * 64 + lane]);
    }
    int running = 0;
    int* nbr_row = nbr + (size_t)row * CAP;
    for (int ci = 0; ci < 4; ++ci) {
      const int cur = (p0 + ci) & 3;
      if (ci < 3) {  // prefetch next (staggered) chunk while consuming current
        const u32x4* cp = rowp + (((p0 + ci + 1) & 3) * 512);
#pragma unroll
        for (int i = 0; i < 8; ++i) vn[i] = __builtin_nontemporal_load(&cp[i * 64 + lane]);
      }
      int c = 0;
#pragma unroll
      for (int i = 0; i < 8; ++i)
        c += (v[i].x != 0u) + (v[i].y != 0u) + (v[i].z != 0u) + (v[i].w != 0u);
      int incl = c;  // wave-inclusive prefix scan, shuffles only
#pragma unroll
      for (int s = 1; s < 64; s <<= 1) {
        int n = __shfl_up(incl, s);
        if (lane >= s) incl += n;
      }
      int off = running + incl - c;
      running += __shfl(incl, 63);
      const int colbase = cur * 2048;
#pragma unroll
      for (int i = 0; i < 8; ++i) {
        if (v[i].x | v[i].y | v[i].z | v[i].w) {
          const int col = colbase + (i * 64 + lane) * 4;
          if (v[i].x) { if (off < CAP) nbr_row[off] = col + 0; ++off; }
          if (v[i].y) { if (off < CAP) nbr_row[off] = col + 1; ++off; }
          if (v[i].z) { if (off < CAP) nbr_row[off] = col + 2; ++off; }
          if (v[i].w) { if (off < CAP) nbr_row[off] = col + 3; ++off; }
        }
      }
#pragma unroll
      for (int i = 0; i < 8; ++i) v[i] = vn[i];
    }
    if (lane == 0) {
      cnt[row] = running;
      dinv[row] = rsqrtf((float)running + 1.0f);
    }
  } else {
    // ---- encode path: x -> h1 -> h ; msg_raw = h @ wg.T (unscaled)
    const int n0 = q * ETILE;
    if (t < 128) {  // stage x tile: 16x32 floats = 128 float4
      int row = t >> 3, k4 = (t & 7) * 4;
      *(float4*)&bufA[row][k4] = *(const float4*)&x[(size_t)(n0 + row) * 32 + k4];
    }
    layer_op<ETILE, 32, 32, 64, true, true, 0>(bufA, nullptr, bufB, Wb, w1, b1, nullptr, nullptr, n0, t);
    layer_op<ETILE, 64, 64, 128, true, true, 0>(bufB, nullptr, bufA, Wb, w2, b2, h_out, nullptr, n0, t);
    layer_op<ETILE, 128, 128, 128, false, false, 0>(bufA, nullptr, nullptr, Wb, wg, nullptr, msg_out, nullptr, n0, t);
  }
}

// ---------------------------------------------------------------------------
// Kernel B: fused agg + decode per 8-node tile. The gather applies dinv_j
// via fmaf (replaces the plain add — free), g1 lives in LDS (no 4MB global
// round-trip), and the decoder runs immediately on the same tile.
// ---------------------------------------------------------------------------
__global__ __launch_bounds__(256) void agg_decode_kernel(
    const int* __restrict__ cnt, const float* __restrict__ dinv,
    const int* __restrict__ nbr, const float* __restrict__ msg,
    const float* __restrict__ adj, const float* __restrict__ h,
    const float* __restrict__ bg,
    const float* __restrict__ wd, const float* __restrict__ bd,
    const float* __restrict__ wp1, const float* __restrict__ bp1,
    const float* __restrict__ wp2, const float* __restrict__ bp2,
    const float* __restrict__ wo, const float* __restrict__ bo,
    const float* __restrict__ mask, float* __restrict__ out) {
  __shared__ float bufA[DTILE][AST];
  __shared__ float bufB[DTILE][AST];
  __shared__ float bufH[DTILE][AST];
  __shared__ float Wb[32][WST];
  const int t = threadIdx.x;
  const int n0 = blockIdx.x * DTILE;
  {  // stage h tile early (8x128 floats = 256 float4; latency hides under agg)
    int row = t >> 5, k4 = (t & 31) * 4;
    *(float4*)&bufH[row][k4] = *(const float4*)&h[(size_t)(n0 + row) * 128 + k4];
  }
  // ---- aggregation: 4 rows per 128-thread group, 4 accumulators/thread.
  const int f = t & 127;
  const int g = t >> 7;
  const int rbase = n0 + g * 4;
  int c[4];
  float dv[4], acc[4];
  const int* np[4];
  bool ok = true;
#pragma unroll
  for (int k = 0; k < 4; ++k) {
    const int r = rbase + k;
    c[k] = cnt[r];
    dv[k] = dinv[r];
    np[k] = nbr + (size_t)r * CAP;
    acc[k] = dv[k] * msg[(size_t)r * 128 + f];  // self-loop term
    ok = ok && (c[k] <= CAP);
  }
  if (ok) {
    const int cm = max(max(c[0], c[1]), max(c[2], c[3]));
    for (int i = 0; i < cm; i += 2) {
#pragma unroll
      for (int m = 0; m < 2; ++m) {
#pragma unroll
        for (int k = 0; k < 4; ++k) {
          const int ii = i + m;
          const int j = np[k][ii < c[k] ? ii : 0] & (N_NODES - 1);
          const float w = (ii < c[k]) ? dinv[j] : 0.f;
          acc[k] = fmaf(w, msg[(size_t)j * 128 + f], acc[k]);
        }
      }
    }
  } else {  // statistically unreachable dense fallback
#pragma unroll
    for (int k = 0; k < 4; ++k) {
      const int r = rbase + k;
      for (int col = 0; col < N_NODES; ++col)
        if (adj[(size_t)r * N_NODES + col] != 0.f)
          acc[k] += dinv[col] * msg[(size_t)col * 128 + f];
    }
  }
#pragma unroll
  for (int k = 0; k < 4; ++k)
    bufA[g * 4 + k][f] = fmaxf(fmaf(dv[k], acc[k], bg[f]), 0.f);
  // layer_op's first internal __syncthreads orders bufA/bufH writes vs reads.
  layer_op<DTILE, 128, 128, 128, true, true, 0>(bufA, nullptr, bufB, Wb, wd, bd, nullptr, nullptr, n0, t);
  layer_op<DTILE, 256, 128, 128, true, true, 0>(bufB, bufH, bufA, Wb, wp1, bp1, nullptr, nullptr, n0, t);
  layer_op<DTILE, 128, 128, 64, true, true, 0>(bufA, nullptr, bufB, Wb, wp2, bp2, nullptr, nullptr, n0, t);
  layer_op<DTILE, 64, 64, 8, false, true, 1>(bufB, nullptr, nullptr, Wb, wo, bo, out, mask, n0, t);
}

extern "C" void kernel_launch(void* const* d_in, const int* in_sizes, int n_in,
                              void* d_out, int out_size, void* d_ws, size_t ws_size,
                              hipStream_t stream) {
  const float* x    = (const float*)d_in[0];
  const float* adj  = (const float*)d_in[1];
  const float* mask = (const float*)d_in[2];
  const float* w1   = (const float*)d_in[3];
  const float* b1   = (const float*)d_in[4];
  const float* w2   = (const float*)d_in[5];
  const float* b2   = (const float*)d_in[6];
  const float* wg   = (const float*)d_in[7];
  const float* bg   = (const float*)d_in[8];
  const float* wd   = (const float*)d_in[9];
  const float* bd   = (const float*)d_in[10];
  const float* wp1  = (const float*)d_in[11];
  const float* bp1  = (const float*)d_in[12];
  const float* wp2  = (const float*)d_in[13];
  const float* bp2  = (const float*)d_in[14];
  const float* wo   = (const float*)d_in[15];
  const float* bo   = (const float*)d_in[16];
  float* out = (float*)d_out;

  float* ws = (float*)d_ws;
  float* h    = ws; ws += (size_t)N_NODES * 128;
  float* msg  = ws; ws += (size_t)N_NODES * 128;
  float* dinv = ws; ws += N_NODES;
  int* cnt = (int*)ws; ws += N_NODES;
  int* nbr = (int*)ws;  // N_NODES * CAP ints

  // A: 2048 scan units + 512 encode units, interleaved 4:1 for co-residency.
  fused_scan_encode_kernel<<<2560, 256, 0, stream>>>(
      adj, cnt, dinv, nbr, x, w1, b1, w2, b2, wg, h, msg);
  // B: agg (g1 in LDS) + decode, 8 nodes per block.
  agg_decode_kernel<<<N_NODES / DTILE, 256, 0, stream>>>(
      cnt, dinv, nbr, msg, adj, h, bg, wd, bd, wp1, bp1, wp2, bp2, wo, bo, mask, out);
}

// Round 3
// 430.609 us; speedup vs baseline: 1.1740x; 1.1740x over previous
//
#include <hip/hip_runtime.h>

#define N_NODES 8192
#define CAP 128    // neighbor capacity; Binomial(8192,1/256): P(deg>128) ~ 0
#define ETILE 16   // nodes per encoder tile
constexpr int AST = 132;  // activation LDS row stride (floats), 16B-aligned
constexpr int WST = 129;  // weight LDS row stride (k-major), +1 pad

typedef unsigned u32x4 __attribute__((ext_vector_type(4)));
typedef unsigned short u16;
typedef __attribute__((ext_vector_type(8))) short bf16x8;
typedef __attribute__((ext_vector_type(4))) float f32x4;

// Pre-split weight fragment regions (in u16 elements): K*F each.
constexpr size_t OFF_WD = 0;                  // 128*128 = 16384
constexpr size_t OFF_WP1 = 16384;             // 256*128 = 32768
constexpr size_t OFF_WP2 = 49152;             // 128*64  = 8192
constexpr size_t OFF_WO = 57344;              // 64*16   = 1024 (cols 8..15 zero-pad)
constexpr size_t WTOT = 58368;

// ---------------------------------------------------------------------------
// Kernel 1: adj scan -> CSR. One row per wave, zero barriers, chunk-level
// double buffer (proven R0 structure). NONTEMPORAL streaming loads.
// ---------------------------------------------------------------------------
__global__ __launch_bounds__(256, 4) void scan_kernel(
    const float* __restrict__ adj, int* __restrict__ cnt,
    int* __restrict__ nbr) {
  const int t = threadIdx.x;
  const int lane = t & 63;
  const int row = blockIdx.x * 4 + (t >> 6);
  const u32x4* rowp = (const u32x4*)(adj + (size_t)row * N_NODES);
  u32x4 v[8], vn[8];
#pragma unroll
  for (int i = 0; i < 8; ++i) v[i] = __builtin_nontemporal_load(&rowp[i * 64 + lane]);
  int running = 0;
  int* nbr_row = nbr + (size_t)row * CAP;
  for (int ch = 0; ch < 4; ++ch) {
    if (ch < 3) {  // prefetch next chunk while consuming current
      const u32x4* cp = rowp + (ch + 1) * 512;
#pragma unroll
      for (int i = 0; i < 8; ++i) vn[i] = __builtin_nontemporal_load(&cp[i * 64 + lane]);
    }
    int c = 0;
#pragma unroll
    for (int i = 0; i < 8; ++i)
      c += (v[i].x != 0u) + (v[i].y != 0u) + (v[i].z != 0u) + (v[i].w != 0u);
    int incl = c;  // wave-inclusive prefix scan, shuffles only
#pragma unroll
    for (int s = 1; s < 64; s <<= 1) {
      int n = __shfl_up(incl, s);
      if (lane >= s) incl += n;
    }
    int off = running + incl - c;
    running += __shfl(incl, 63);
    const int colbase = ch * 2048;
#pragma unroll
    for (int i = 0; i < 8; ++i) {
      if (v[i].x | v[i].y | v[i].z | v[i].w) {
        const int col = colbase + (i * 64 + lane) * 4;
        if (v[i].x) { if (off < CAP) nbr_row[off] = col + 0; ++off; }
        if (v[i].y) { if (off < CAP) nbr_row[off] = col + 1; ++off; }
        if (v[i].z) { if (off < CAP) nbr_row[off] = col + 2; ++off; }
        if (v[i].w) { if (off < CAP) nbr_row[off] = col + 3; ++off; }
      }
    }
#pragma unroll
    for (int i = 0; i < 8; ++i) v[i] = vn[i];
  }
  if (lane == 0) cnt[row] = running;
}

// ---------------------------------------------------------------------------
// LDS-resident MLP layer (R0 version, used by encoder only).
// SCALEMODE: 0 = none, 1 = rowscale[node] (mask), 2 = rsqrt(cnt[node]+1).
// ---------------------------------------------------------------------------
template <int TILE, int K, int KSPLIT, int F, bool RELU, bool BIAS, int SCALEMODE>
__device__ __forceinline__ void layer_op(
    const float (*__restrict__ A0)[AST], const float (*__restrict__ A1)[AST],
    float (*__restrict__ Aout)[AST], float (*__restrict__ Wb)[WST],
    const float* __restrict__ W, const float* __restrict__ bias,
    float* __restrict__ gout, const float* __restrict__ rowscale,
    const int* __restrict__ degcnt, int n0, int t) {
  constexpr int KC = 32;
  constexpr int NCH = K / KC;
  constexpr int ACT = (F * TILE < 256) ? F * TILE : 256;
  constexpr int RS = ACT / F;
  constexpr int RPT = TILE / RS;
  const int c = t % F;
  const int rb = t / F;
  float acc[RPT];
#pragma unroll
  for (int i = 0; i < RPT; ++i) acc[i] = 0.f;

  for (int ch = 0; ch < NCH; ++ch) {
#pragma unroll
    for (int i = 0; i < (F * KC + 255) / 256; ++i) {  // stage W chunk, k-major
      int lin = t + i * 256;
      if ((F * KC) % 256 == 0 || lin < F * KC) {
        int k = lin % KC, f = lin / KC;
        Wb[k][f] = W[(size_t)f * K + ch * KC + k];
      }
    }
    __syncthreads();
    if (t < ACT) {
      const float (*__restrict__ As)[AST] = (ch * KC < KSPLIT) ? A0 : A1;
      const int kb = (ch * KC < KSPLIT) ? ch * KC : ch * KC - KSPLIT;
#pragma unroll
      for (int kg = 0; kg < KC / 4; ++kg) {
        float w0 = Wb[kg * 4 + 0][c];
        float w1v = Wb[kg * 4 + 1][c];
        float w2v = Wb[kg * 4 + 2][c];
        float w3v = Wb[kg * 4 + 3][c];
#pragma unroll
        for (int i = 0; i < RPT; ++i) {
          const float4 a = *(const float4*)&As[rb + i * RS][kb + kg * 4];
          acc[i] = fmaf(a.x, w0, acc[i]);
          acc[i] = fmaf(a.y, w1v, acc[i]);
          acc[i] = fmaf(a.z, w2v, acc[i]);
          acc[i] = fmaf(a.w, w3v, acc[i]);
        }
      }
    }
    __syncthreads();
  }
  if (t < ACT) {
#pragma unroll
    for (int i = 0; i < RPT; ++i) {
      float v = acc[i];
      if (BIAS) v += bias[c];
      if (RELU) v = fmaxf(v, 0.f);
      int node = n0 + rb + i * RS;
      if (SCALEMODE == 1) v *= rowscale[node];
      if (SCALEMODE == 2) v *= rsqrtf((float)degcnt[node] + 1.0f);
      if (Aout) Aout[rb + i * RS][c] = v;
      if (gout) gout[(size_t)node * F + c] = v;
    }
  }
}

// ---------------------------------------------------------------------------
// Kernel 2: encoder x -> h1 -> h ; msg = (h @ wg.T) * dinv  (R0 verbatim)
// ---------------------------------------------------------------------------
__global__ __launch_bounds__(256) void encode_kernel(
    const float* __restrict__ x,
    const float* __restrict__ w1, const float* __restrict__ b1,
    const float* __restrict__ w2, const float* __restrict__ b2,
    const float* __restrict__ wg, const int* __restrict__ cnt,
    float* __restrict__ h_out, float* __restrict__ msg_out) {
  __shared__ float bufA[ETILE][AST];
  __shared__ float bufB[ETILE][AST];
  __shared__ float Wb[32][WST];
  const int t = threadIdx.x;
  const int n0 = blockIdx.x * ETILE;
  if (t < 128) {  // stage x tile: 16x32 floats = 128 float4
    int row = t >> 3, k4 = (t & 7) * 4;
    *(float4*)&bufA[row][k4] = *(const float4*)&x[(size_t)(n0 + row) * 32 + k4];
  }
  layer_op<ETILE, 32, 32, 64, true, true, 0>(bufA, nullptr, bufB, Wb, w1, b1, nullptr, nullptr, nullptr, n0, t);
  layer_op<ETILE, 64, 64, 128, true, true, 0>(bufB, nullptr, bufA, Wb, w2, b2, h_out, nullptr, nullptr, n0, t);
  layer_op<ETILE, 128, 128, 128, false, false, 2>(bufA, nullptr, nullptr, Wb, wg, nullptr, msg_out, nullptr, cnt, n0, t);
}

// ---------------------------------------------------------------------------
// Kernel 3: agg (R0 verbatim). msg is pre-scaled by dinv.
// ---------------------------------------------------------------------------
__global__ __launch_bounds__(256) void agg_kernel(
    const int* __restrict__ cnt, const int* __restrict__ nbr,
    const float* __restrict__ msg, const float* __restrict__ bg,
    const float* __restrict__ adj, float* __restrict__ g1) {
  const int t = threadIdx.x;
  const int f = t & 127;
  const int rA = blockIdx.x * 4 + (t >> 7) * 2;
  const int rB = rA + 1;
  const int cA = cnt[rA], cB = cnt[rB];
  float a0 = msg[(size_t)rA * 128 + f];  // self-loop terms (msg pre-scaled)
  float a1 = msg[(size_t)rB * 128 + f];
  if (cA <= CAP && cB <= CAP) {
    const int* nA = nbr + (size_t)rA * CAP;
    const int* nB = nbr + (size_t)rB * CAP;
    const int cm = max(cA, cB);
    for (int i = 0; i < cm; i += 4) {
#pragma unroll
      for (int k = 0; k < 4; ++k) {
        const int ii = i + k;
        int jA = nA[ii < cA ? ii : 0] & (N_NODES - 1);
        int jB = nB[ii < cB ? ii : 0] & (N_NODES - 1);
        float vA = msg[(size_t)jA * 128 + f];
        float vB = msg[(size_t)jB * 128 + f];
        a0 += (ii < cA) ? vA : 0.f;
        a1 += (ii < cB) ? vB : 0.f;
      }
    }
  } else {  // statistically unreachable dense fallback
    a0 = msg[(size_t)rA * 128 + f];
    a1 = msg[(size_t)rB * 128 + f];
    for (int col = 0; col < N_NODES; ++col) {
      if (adj[(size_t)rA * N_NODES + col] != 0.f) a0 += msg[(size_t)col * 128 + f];
      if (adj[(size_t)rB * N_NODES + col] != 0.f) a1 += msg[(size_t)col * 128 + f];
    }
  }
  float o0 = fmaf(rsqrtf((float)cA + 1.0f), a0, bg[f]);
  float o1 = fmaf(rsqrtf((float)cB + 1.0f), a1, bg[f]);
  g1[(size_t)rA * 128 + f] = fmaxf(o0, 0.f);
  g1[(size_t)rB * 128 + f] = fmaxf(o1, 0.f);
}

// ---------------------------------------------------------------------------
// Kernel 0: pre-split decoder weights into MFMA-fragment-major bf16 pairs.
// Region element (kstep,ftile,lane,j) holds W[f = ftile*16 + (lane&15)]
// [k = kstep*32 + (lane>>4)*8 + j], split as hi=trunc_bf16(w),
// lo=trunc_bf16(w - hi). A-frags use the SAME (lane,j)->k map, so any
// internal HW k-permutation cancels between A and B.
// ---------------------------------------------------------------------------
__global__ __launch_bounds__(256) void prep_weights(
    const float* __restrict__ wd, const float* __restrict__ wp1,
    const float* __restrict__ wp2, const float* __restrict__ wo,
    u16* __restrict__ bh, u16* __restrict__ bl) {
  const int gid = blockIdx.x * 256 + threadIdx.x;
  if (gid >= (int)WTOT) return;
  const float* W; int K, F; size_t off; int rel; bool pad = false;
  if (gid < 16384)      { W = wd;  K = 128; F = 128; off = OFF_WD;  rel = gid; }
  else if (gid < 49152) { W = wp1; K = 256; F = 128; off = OFF_WP1; rel = gid - 16384; }
  else if (gid < 57344) { W = wp2; K = 128; F = 64;  off = OFF_WP2; rel = gid - 49152; }
  else                  { W = wo;  K = 64;  F = 16;  off = OFF_WO;  rel = gid - 57344; pad = true; }
  const int j = rel & 7, lane = (rel >> 3) & 63, t2 = rel >> 9;
  const int nf = F >> 4;
  const int ftile = t2 % nf, kstep = t2 / nf;
  const int k = kstep * 32 + ((lane >> 4) << 3) + j;
  const int f = ftile * 16 + (lane & 15);
  const float v = (pad && f >= 8) ? 0.f : W[(size_t)f * K + k];
  const unsigned u = __float_as_uint(v);
  const unsigned uh = u & 0xffff0000u;
  const float r = v - __uint_as_float(uh);
  bh[off + rel] = (u16)(uh >> 16);
  bl[off + rel] = (u16)(__float_as_uint(r) >> 16);
}

// ---------------------------------------------------------------------------
// MFMA split-bf16 layer: one wave computes a 16-node x F output tile.
// A fragment: lane holds act[row = lane&15][k = ks*32 + (lane>>4)*8 + j].
// C/D mapping (HW-verified): col = lane&15, row = (lane>>4)*4 + r.
// D += Ahi*Bhi + Ahi*Blo + Alo*Bhi  (lo*lo ~ 2^-16 rel, dropped).
// ---------------------------------------------------------------------------
template <int K, int F, int KSPLIT, bool RELU, bool FINAL>
__device__ __forceinline__ void mfma_layer(
    const float (*__restrict__ A0)[AST], const float (*__restrict__ A1)[AST],
    const u16* __restrict__ Bh, const u16* __restrict__ Bl,
    const float* __restrict__ bias, float (*__restrict__ O)[AST],
    float* __restrict__ gout, const float* __restrict__ mask,
    int nbase, int lane) {
  constexpr int NK = K / 32, NF = F / 16;
  f32x4 acc[NF];
  const f32x4 zz = {0.f, 0.f, 0.f, 0.f};
#pragma unroll
  for (int i = 0; i < NF; ++i) acc[i] = zz;
  const int arow = lane & 15;
  const int kgrp = (lane >> 4) << 3;
#pragma unroll
  for (int ks = 0; ks < NK; ++ks) {
    const float* ap = (ks * 32 < KSPLIT) ? &A0[arow][ks * 32 + kgrp]
                                         : &A1[arow][ks * 32 - KSPLIT + kgrp];
    const float4 p0 = *(const float4*)ap;
    const float4 p1 = *(const float4*)(ap + 4);
    const float av[8] = {p0.x, p0.y, p0.z, p0.w, p1.x, p1.y, p1.z, p1.w};
    bf16x8 ahi, alo;
#pragma unroll
    for (int j = 0; j < 8; ++j) {
      const unsigned u = __float_as_uint(av[j]);
      const unsigned uh = u & 0xffff0000u;
      const float r = av[j] - __uint_as_float(uh);
      ahi[j] = (short)(uh >> 16);
      alo[j] = (short)(__float_as_uint(r) >> 16);
    }
#pragma unroll
    for (int ft = 0; ft < NF; ++ft) {
      const size_t idx = ((size_t)(ks * NF + ft) * 64 + lane) * 8;
      const bf16x8 wh = *(const bf16x8*)(Bh + idx);
      const bf16x8 wl = *(const bf16x8*)(Bl + idx);
      acc[ft] = __builtin_amdgcn_mfma_f32_16x16x32_bf16(ahi, wh, acc[ft], 0, 0, 0);
      acc[ft] = __builtin_amdgcn_mfma_f32_16x16x32_bf16(ahi, wl, acc[ft], 0, 0, 0);
      acc[ft] = __builtin_amdgcn_mfma_f32_16x16x32_bf16(alo, wh, acc[ft], 0, 0, 0);
    }
  }
#pragma unroll
  for (int ft = 0; ft < NF; ++ft) {
    const int f = ft * 16 + (lane & 15);
    if (FINAL && f >= 8) continue;  // zero-padded columns, not stored
    const float bv = bias[f];
#pragma unroll
    for (int r = 0; r < 4; ++r) {
      const int row = ((lane >> 4) << 2) + r;
      float v = acc[ft][r] + bv;
      if (RELU) v = fmaxf(v, 0.f);
      if (!FINAL) O[row][f] = v;
      else gout[(size_t)(nbase + row) * 8 + f] = v * mask[nbase + row];
    }
  }
}

// ---------------------------------------------------------------------------
// Kernel 4: MFMA decoder. 128 threads = 2 waves; each wave owns 16 nodes
// with wave-private LDS activation buffers. Weights stream straight from
// L2 in fragment-major pre-split form (no LDS staging, no per-chunk
// barriers). g1 -> g2 -> p1([g2|h]) -> p2 -> out * mask.
// ---------------------------------------------------------------------------
__global__ __launch_bounds__(128) void mfma_decode(
    const float* __restrict__ g1, const float* __restrict__ h,
    const u16* __restrict__ bh, const u16* __restrict__ bl,
    const float* __restrict__ bd, const float* __restrict__ bp1,
    const float* __restrict__ bp2, const float* __restrict__ bo,
    const float* __restrict__ mask, float* __restrict__ out) {
  __shared__ float actA[2][16][AST];
  __shared__ float actB[2][16][AST];
  __shared__ float actH[2][16][AST];
  const int t = threadIdx.x;
  const int w = t >> 6, lane = t & 63;
  const int n0 = blockIdx.x * 32 + w * 16;
#pragma unroll
  for (int i = 0; i < 8; ++i) {  // stage g1 + h: 16 rows x 32 float4 each
    const int fi = i * 64 + lane;
    const int row = fi >> 5, c4 = (fi & 31) * 4;
    *(float4*)&actA[w][row][c4] = *(const float4*)&g1[(size_t)(n0 + row) * 128 + c4];
    *(float4*)&actH[w][row][c4] = *(const float4*)&h[(size_t)(n0 + row) * 128 + c4];
  }
  __syncthreads();
  mfma_layer<128, 128, 128, true, false>(actA[w], actA[w], bh + OFF_WD, bl + OFF_WD,
                                         bd, actB[w], nullptr, nullptr, n0, lane);
  __syncthreads();
  mfma_layer<256, 128, 128, true, false>(actB[w], actH[w], bh + OFF_WP1, bl + OFF_WP1,
                                         bp1, actA[w], nullptr, nullptr, n0, lane);
  __syncthreads();
  mfma_layer<128, 64, 128, true, false>(actA[w], actA[w], bh + OFF_WP2, bl + OFF_WP2,
                                        bp2, actB[w], nullptr, nullptr, n0, lane);
  __syncthreads();
  mfma_layer<64, 16, 128, false, true>(actB[w], actB[w], bh + OFF_WO, bl + OFF_WO,
                                       bo, nullptr, out, mask, n0, lane);
}

extern "C" void kernel_launch(void* const* d_in, const int* in_sizes, int n_in,
                              void* d_out, int out_size, void* d_ws, size_t ws_size,
                              hipStream_t stream) {
  const float* x    = (const float*)d_in[0];
  const float* adj  = (const float*)d_in[1];
  const float* mask = (const float*)d_in[2];
  const float* w1   = (const float*)d_in[3];
  const float* b1   = (const float*)d_in[4];
  const float* w2   = (const float*)d_in[5];
  const float* b2   = (const float*)d_in[6];
  const float* wg   = (const float*)d_in[7];
  const float* bg   = (const float*)d_in[8];
  const float* wd   = (const float*)d_in[9];
  const float* bd   = (const float*)d_in[10];
  const float* wp1  = (const float*)d_in[11];
  const float* bp1  = (const float*)d_in[12];
  const float* wp2  = (const float*)d_in[13];
  const float* bp2  = (const float*)d_in[14];
  const float* wo   = (const float*)d_in[15];
  const float* bo   = (const float*)d_in[16];
  float* out = (float*)d_out;

  float* ws = (float*)d_ws;
  float* h    = ws; ws += (size_t)N_NODES * 128;
  float* msg  = ws; ws += (size_t)N_NODES * 128;
  float* g1   = ws; ws += (size_t)N_NODES * 128;
  int* cnt = (int*)ws; ws += N_NODES;
  int* nbr = (int*)ws; ws += (size_t)N_NODES * CAP;
  u16* bh = (u16*)ws;
  u16* bl = bh + WTOT;

  prep_weights<<<(int)((WTOT + 255) / 256), 256, 0, stream>>>(wd, wp1, wp2, wo, bh, bl);
  scan_kernel<<<N_NODES / 4, 256, 0, stream>>>(adj, cnt, nbr);
  encode_kernel<<<N_NODES / ETILE, 256, 0, stream>>>(x, w1, b1, w2, b2, wg, cnt, h, msg);
  agg_kernel<<<N_NODES / 4, 256, 0, stream>>>(cnt, nbr, msg, bg, adj, g1);
  mfma_decode<<<N_NODES / 32, 128, 0, stream>>>(g1, h, bh, bl, bd, bp1, bp2, bo, mask, out);
}

// Round 4
// 430.581 us; speedup vs baseline: 1.1741x; 1.0001x over previous
//
#include <hip/hip_runtime.h>

#define N_NODES 8192
#define CAP 128    // neighbor capacity; Binomial(8192,1/256): P(deg>128) ~ 0
constexpr int AST = 132;  // activation LDS row stride (floats), 16B-aligned

typedef unsigned u32x4 __attribute__((ext_vector_type(4)));
typedef unsigned short u16;
typedef __attribute__((ext_vector_type(8))) short bf16x8;
typedef __attribute__((ext_vector_type(4))) float f32x4;

// Pre-split weight fragment regions (in u16 elements): K*F each.
constexpr size_t OFF_WD  = 0;        // 128*128 = 16384
constexpr size_t OFF_WP1 = 16384;    // 256*128 = 32768
constexpr size_t OFF_WP2 = 49152;    // 128*64  = 8192
constexpr size_t OFF_WO  = 57344;    // 64*16   = 1024 (cols 8..15 zero-pad)
constexpr size_t OFF_W1  = 58368;    // 32*64   = 2048
constexpr size_t OFF_W2  = 60416;    // 64*128  = 8192
constexpr size_t OFF_WG  = 68608;    // 128*128 = 16384
constexpr size_t WTOT    = 84992;

// ---------------------------------------------------------------------------
// Kernel 1: adj scan -> CSR. One row per wave, zero barriers, chunk-level
// double buffer (proven R0 structure). NONTEMPORAL streaming loads.
// ---------------------------------------------------------------------------
__global__ __launch_bounds__(256, 4) void scan_kernel(
    const float* __restrict__ adj, int* __restrict__ cnt,
    int* __restrict__ nbr) {
  const int t = threadIdx.x;
  const int lane = t & 63;
  const int row = blockIdx.x * 4 + (t >> 6);
  const u32x4* rowp = (const u32x4*)(adj + (size_t)row * N_NODES);
  u32x4 v[8], vn[8];
#pragma unroll
  for (int i = 0; i < 8; ++i) v[i] = __builtin_nontemporal_load(&rowp[i * 64 + lane]);
  int running = 0;
  int* nbr_row = nbr + (size_t)row * CAP;
  for (int ch = 0; ch < 4; ++ch) {
    if (ch < 3) {  // prefetch next chunk while consuming current
      const u32x4* cp = rowp + (ch + 1) * 512;
#pragma unroll
      for (int i = 0; i < 8; ++i) vn[i] = __builtin_nontemporal_load(&cp[i * 64 + lane]);
    }
    int c = 0;
#pragma unroll
    for (int i = 0; i < 8; ++i)
      c += (v[i].x != 0u) + (v[i].y != 0u) + (v[i].z != 0u) + (v[i].w != 0u);
    int incl = c;  // wave-inclusive prefix scan, shuffles only
#pragma unroll
    for (int s = 1; s < 64; s <<= 1) {
      int n = __shfl_up(incl, s);
      if (lane >= s) incl += n;
    }
    int off = running + incl - c;
    running += __shfl(incl, 63);
    const int colbase = ch * 2048;
#pragma unroll
    for (int i = 0; i < 8; ++i) {
      if (v[i].x | v[i].y | v[i].z | v[i].w) {
        const int col = colbase + (i * 64 + lane) * 4;
        if (v[i].x) { if (off < CAP) nbr_row[off] = col + 0; ++off; }
        if (v[i].y) { if (off < CAP) nbr_row[off] = col + 1; ++off; }
        if (v[i].z) { if (off < CAP) nbr_row[off] = col + 2; ++off; }
        if (v[i].w) { if (off < CAP) nbr_row[off] = col + 3; ++off; }
      }
    }
#pragma unroll
    for (int i = 0; i < 8; ++i) v[i] = vn[i];
  }
  if (lane == 0) cnt[row] = running;
}

// ---------------------------------------------------------------------------
// Kernel 3: agg (R0 verbatim). msg is pre-scaled by dinv.
// ---------------------------------------------------------------------------
__global__ __launch_bounds__(256) void agg_kernel(
    const int* __restrict__ cnt, const int* __restrict__ nbr,
    const float* __restrict__ msg, const float* __restrict__ bg,
    const float* __restrict__ adj, float* __restrict__ g1) {
  const int t = threadIdx.x;
  const int f = t & 127;
  const int rA = blockIdx.x * 4 + (t >> 7) * 2;
  const int rB = rA + 1;
  const int cA = cnt[rA], cB = cnt[rB];
  float a0 = msg[(size_t)rA * 128 + f];  // self-loop terms (msg pre-scaled)
  float a1 = msg[(size_t)rB * 128 + f];
  if (cA <= CAP && cB <= CAP) {
    const int* nA = nbr + (size_t)rA * CAP;
    const int* nB = nbr + (size_t)rB * CAP;
    const int cm = max(cA, cB);
    for (int i = 0; i < cm; i += 4) {
#pragma unroll
      for (int k = 0; k < 4; ++k) {
        const int ii = i + k;
        int jA = nA[ii < cA ? ii : 0] & (N_NODES - 1);
        int jB = nB[ii < cB ? ii : 0] & (N_NODES - 1);
        float vA = msg[(size_t)jA * 128 + f];
        float vB = msg[(size_t)jB * 128 + f];
        a0 += (ii < cA) ? vA : 0.f;
        a1 += (ii < cB) ? vB : 0.f;
      }
    }
  } else {  // statistically unreachable dense fallback
    a0 = msg[(size_t)rA * 128 + f];
    a1 = msg[(size_t)rB * 128 + f];
    for (int col = 0; col < N_NODES; ++col) {
      if (adj[(size_t)rA * N_NODES + col] != 0.f) a0 += msg[(size_t)col * 128 + f];
      if (adj[(size_t)rB * N_NODES + col] != 0.f) a1 += msg[(size_t)col * 128 + f];
    }
  }
  float o0 = fmaf(rsqrtf((float)cA + 1.0f), a0, bg[f]);
  float o1 = fmaf(rsqrtf((float)cB + 1.0f), a1, bg[f]);
  g1[(size_t)rA * 128 + f] = fmaxf(o0, 0.f);
  g1[(size_t)rB * 128 + f] = fmaxf(o1, 0.f);
}

// ---------------------------------------------------------------------------
// Kernel 0: pre-split ALL MLP weights into MFMA-fragment-major bf16 pairs.
// Region element (kstep,ftile,lane,j) holds W[f = ftile*16 + (lane&15)]
// [k = kstep*32 + (lane>>4)*8 + j], split hi=trunc_bf16(w),
// lo=trunc_bf16(w - hi). A-frags use the SAME (lane,j)->k map, so any
// internal HW k-permutation cancels between A and B.
// ---------------------------------------------------------------------------
__global__ __launch_bounds__(256) void prep_weights(
    const float* __restrict__ wd, const float* __restrict__ wp1,
    const float* __restrict__ wp2, const float* __restrict__ wo,
    const float* __restrict__ w1, const float* __restrict__ w2,
    const float* __restrict__ wg,
    u16* __restrict__ bh, u16* __restrict__ bl) {
  const int gid = blockIdx.x * 256 + threadIdx.x;
  if (gid >= (int)WTOT) return;
  const float* W; int K, F; size_t off; int rel; bool pad = false;
  if (gid < 16384)      { W = wd;  K = 128; F = 128; off = OFF_WD;  rel = gid; }
  else if (gid < 49152) { W = wp1; K = 256; F = 128; off = OFF_WP1; rel = gid - 16384; }
  else if (gid < 57344) { W = wp2; K = 128; F = 64;  off = OFF_WP2; rel = gid - 49152; }
  else if (gid < 58368) { W = wo;  K = 64;  F = 16;  off = OFF_WO;  rel = gid - 57344; pad = true; }
  else if (gid < 60416) { W = w1;  K = 32;  F = 64;  off = OFF_W1;  rel = gid - 58368; }
  else if (gid < 68608) { W = w2;  K = 64;  F = 128; off = OFF_W2;  rel = gid - 60416; }
  else                  { W = wg;  K = 128; F = 128; off = OFF_WG;  rel = gid - 68608; }
  const int j = rel & 7, lane = (rel >> 3) & 63, t2 = rel >> 9;
  const int nf = F >> 4;
  const int ftile = t2 % nf, kstep = t2 / nf;
  const int k = kstep * 32 + ((lane >> 4) << 3) + j;
  const int f = ftile * 16 + (lane & 15);
  const float v = (pad && f >= 8) ? 0.f : W[(size_t)f * K + k];
  const unsigned u = __float_as_uint(v);
  const unsigned uh = u & 0xffff0000u;
  const float r = v - __uint_as_float(uh);
  bh[off + rel] = (u16)(uh >> 16);
  bl[off + rel] = (u16)(__float_as_uint(r) >> 16);
}

// ---------------------------------------------------------------------------
// MFMA split-bf16 layer: one wave computes a 16-node x F output tile.
// A fragment: lane holds act[row = lane&15][k = ks*32 + (lane>>4)*8 + j].
// C/D mapping (HW-verified): col = lane&15, row = (lane>>4)*4 + r.
// D += Ahi*Bhi + Ahi*Blo + Alo*Bhi  (lo*lo ~ 2^-16 rel, dropped).
// SCALEMODE: 0 none, 1 mask[node] (with F==16: only f<8 stored), 2 dinv(cnt).
// ---------------------------------------------------------------------------
template <int K, int F, int KSPLIT, int SA, int SO, bool RELU, bool BIAS, int SCALEMODE>
__device__ __forceinline__ void mfma_layer(
    const float (*__restrict__ A0)[SA], const float (*__restrict__ A1)[SA],
    const u16* __restrict__ Bh, const u16* __restrict__ Bl,
    const float* __restrict__ bias, float (*__restrict__ O)[SO],
    float* __restrict__ gout, int gstride,
    const float* __restrict__ mask, const int* __restrict__ cntp,
    int nbase, int lane) {
  constexpr int NK = K / 32, NF = F / 16;
  f32x4 acc[NF];
  const f32x4 zz = {0.f, 0.f, 0.f, 0.f};
#pragma unroll
  for (int i = 0; i < NF; ++i) acc[i] = zz;
  const int arow = lane & 15;
  const int kgrp = (lane >> 4) << 3;
#pragma unroll
  for (int ks = 0; ks < NK; ++ks) {
    const float* ap = (ks * 32 < KSPLIT) ? &A0[arow][ks * 32 + kgrp]
                                         : &A1[arow][ks * 32 - KSPLIT + kgrp];
    const float4 p0 = *(const float4*)ap;
    const float4 p1 = *(const float4*)(ap + 4);
    const float av[8] = {p0.x, p0.y, p0.z, p0.w, p1.x, p1.y, p1.z, p1.w};
    bf16x8 ahi, alo;
#pragma unroll
    for (int j = 0; j < 8; ++j) {
      const unsigned u = __float_as_uint(av[j]);
      const unsigned uh = u & 0xffff0000u;
      const float r = av[j] - __uint_as_float(uh);
      ahi[j] = (short)(uh >> 16);
      alo[j] = (short)(__float_as_uint(r) >> 16);
    }
#pragma unroll
    for (int ft = 0; ft < NF; ++ft) {
      const size_t idx = ((size_t)(ks * NF + ft) * 64 + lane) * 8;
      const bf16x8 wh = *(const bf16x8*)(Bh + idx);
      const bf16x8 wl = *(const bf16x8*)(Bl + idx);
      acc[ft] = __builtin_amdgcn_mfma_f32_16x16x32_bf16(ahi, wh, acc[ft], 0, 0, 0);
      acc[ft] = __builtin_amdgcn_mfma_f32_16x16x32_bf16(ahi, wl, acc[ft], 0, 0, 0);
      acc[ft] = __builtin_amdgcn_mfma_f32_16x16x32_bf16(alo, wh, acc[ft], 0, 0, 0);
    }
  }
#pragma unroll
  for (int ft = 0; ft < NF; ++ft) {
    const int f = ft * 16 + (lane & 15);
    if (SCALEMODE == 1 && F == 16 && f >= 8) continue;  // zero-padded cols
    const float bv = BIAS ? bias[f] : 0.f;
#pragma unroll
    for (int r = 0; r < 4; ++r) {
      const int row = ((lane >> 4) << 2) + r;
      const int node = nbase + row;
      float v = acc[ft][r];
      if (BIAS) v += bv;
      if (RELU) v = fmaxf(v, 0.f);
      if (SCALEMODE == 1) v *= mask[node];
      if (SCALEMODE == 2) v *= rsqrtf((float)cntp[node] + 1.0f);
      if (O) O[row][f] = v;
      if (gout) gout[(size_t)node * gstride + f] = v;
    }
  }
}

// ---------------------------------------------------------------------------
// Kernel 2: MFMA encoder. 128 threads = 2 waves; each wave owns 16 nodes
// with wave-private LDS buffers. x -> h1 -> h (to global) ;
// msg = (h @ wg.T) * dinv(cnt) (to global). Weights stream from L2 in
// fragment-major pre-split form.
// ---------------------------------------------------------------------------
__global__ __launch_bounds__(128) void mfma_encode(
    const float* __restrict__ x, const u16* __restrict__ bh,
    const u16* __restrict__ bl, const float* __restrict__ b1,
    const float* __restrict__ b2, const int* __restrict__ cnt,
    float* __restrict__ h_out, float* __restrict__ msg_out) {
  __shared__ float actX[2][16][36];
  __shared__ float actH1[2][16][68];
  __shared__ float actH[2][16][AST];
  const int t = threadIdx.x;
  const int w = t >> 6, lane = t & 63;
  const int n0 = blockIdx.x * 32 + w * 16;
#pragma unroll
  for (int i = 0; i < 2; ++i) {  // stage x: 16 rows x 8 float4
    const int fi = i * 64 + lane;
    const int row = fi >> 3, c4 = (fi & 7) * 4;
    *(float4*)&actX[w][row][c4] = *(const float4*)&x[(size_t)(n0 + row) * 32 + c4];
  }
  __syncthreads();
  mfma_layer<32, 64, 32, 36, 68, true, true, 0>(
      actX[w], actX[w], bh + OFF_W1, bl + OFF_W1, b1, actH1[w],
      nullptr, 0, nullptr, nullptr, n0, lane);
  __syncthreads();
  mfma_layer<64, 128, 64, 68, AST, true, true, 0>(
      actH1[w], actH1[w], bh + OFF_W2, bl + OFF_W2, b2, actH[w],
      h_out, 128, nullptr, nullptr, n0, lane);
  __syncthreads();
  mfma_layer<128, 128, 128, AST, AST, false, false, 2>(
      actH[w], actH[w], bh + OFF_WG, bl + OFF_WG, nullptr, (float(*)[AST])nullptr,
      msg_out, 128, nullptr, cnt, n0, lane);
}

// ---------------------------------------------------------------------------
// Kernel 4: MFMA decoder (R3, proven). 2 waves x 16 nodes, wave-private LDS.
// g1 -> g2 -> p1([g2|h]) -> p2 -> out * mask.
// ---------------------------------------------------------------------------
__global__ __launch_bounds__(128) void mfma_decode(
    const float* __restrict__ g1, const float* __restrict__ h,
    const u16* __restrict__ bh, const u16* __restrict__ bl,
    const float* __restrict__ bd, const float* __restrict__ bp1,
    const float* __restrict__ bp2, const float* __restrict__ bo,
    const float* __restrict__ mask, float* __restrict__ out) {
  __shared__ float actA[2][16][AST];
  __shared__ float actB[2][16][AST];
  __shared__ float actH[2][16][AST];
  const int t = threadIdx.x;
  const int w = t >> 6, lane = t & 63;
  const int n0 = blockIdx.x * 32 + w * 16;
#pragma unroll
  for (int i = 0; i < 8; ++i) {  // stage g1 + h: 16 rows x 32 float4 each
    const int fi = i * 64 + lane;
    const int row = fi >> 5, c4 = (fi & 31) * 4;
    *(float4*)&actA[w][row][c4] = *(const float4*)&g1[(size_t)(n0 + row) * 128 + c4];
    *(float4*)&actH[w][row][c4] = *(const float4*)&h[(size_t)(n0 + row) * 128 + c4];
  }
  __syncthreads();
  mfma_layer<128, 128, 128, AST, AST, true, true, 0>(
      actA[w], actA[w], bh + OFF_WD, bl + OFF_WD, bd, actB[w],
      nullptr, 0, nullptr, nullptr, n0, lane);
  __syncthreads();
  mfma_layer<256, 128, 128, AST, AST, true, true, 0>(
      actB[w], actH[w], bh + OFF_WP1, bl + OFF_WP1, bp1, actA[w],
      nullptr, 0, nullptr, nullptr, n0, lane);
  __syncthreads();
  mfma_layer<128, 64, 128, AST, AST, true, true, 0>(
      actA[w], actA[w], bh + OFF_WP2, bl + OFF_WP2, bp2, actB[w],
      nullptr, 0, nullptr, nullptr, n0, lane);
  __syncthreads();
  mfma_layer<64, 16, 128, AST, AST, false, true, 1>(
      actB[w], actB[w], bh + OFF_WO, bl + OFF_WO, bo, (float(*)[AST])nullptr,
      out, 8, mask, nullptr, n0, lane);
}

extern "C" void kernel_launch(void* const* d_in, const int* in_sizes, int n_in,
                              void* d_out, int out_size, void* d_ws, size_t ws_size,
                              hipStream_t stream) {
  const float* x    = (const float*)d_in[0];
  const float* adj  = (const float*)d_in[1];
  const float* mask = (const float*)d_in[2];
  const float* w1   = (const float*)d_in[3];
  const float* b1   = (const float*)d_in[4];
  const float* w2   = (const float*)d_in[5];
  const float* b2   = (const float*)d_in[6];
  const float* wg   = (const float*)d_in[7];
  const float* bg   = (const float*)d_in[8];
  const float* wd   = (const float*)d_in[9];
  const float* bd   = (const float*)d_in[10];
  const float* wp1  = (const float*)d_in[11];
  const float* bp1  = (const float*)d_in[12];
  const float* wp2  = (const float*)d_in[13];
  const float* bp2  = (const float*)d_in[14];
  const float* wo   = (const float*)d_in[15];
  const float* bo   = (const float*)d_in[16];
  float* out = (float*)d_out;

  float* ws = (float*)d_ws;
  float* h    = ws; ws += (size_t)N_NODES * 128;
  float* msg  = ws; ws += (size_t)N_NODES * 128;
  float* g1   = ws; ws += (size_t)N_NODES * 128;
  int* cnt = (int*)ws; ws += N_NODES;
  int* nbr = (int*)ws; ws += (size_t)N_NODES * CAP;
  u16* bh = (u16*)ws;
  u16* bl = bh + WTOT;

  prep_weights<<<(int)((WTOT + 255) / 256), 256, 0, stream>>>(
      wd, wp1, wp2, wo, w1, w2, wg, bh, bl);
  scan_kernel<<<N_NODES / 4, 256, 0, stream>>>(adj, cnt, nbr);
  mfma_encode<<<N_NODES / 32, 128, 0, stream>>>(x, bh, bl, b1, b2, cnt, h, msg);
  agg_kernel<<<N_NODES / 4, 256, 0, stream>>>(cnt, nbr, msg, bg, adj, g1);
  mfma_decode<<<N_NODES / 32, 128, 0, stream>>>(g1, h, bh, bl, bd, bp1, bp2, bo, mask, out);
}